// Round 2
// baseline (257.927 us; speedup 1.0000x reference)
//
#include <hip/hip_runtime.h>
#include <math.h>

#define NPTS 262144
#define KC 512
#define DD 64
#define HALF (NPTS / 2)

// Kernel 1: copy centroids to output 0 and compute c_sq (numpy pairwise-8 order).
__global__ __launch_bounds__(256) void prep_kernel(const float* __restrict__ c,
                                                   float* __restrict__ out_c,
                                                   float* __restrict__ c_sq) {
    int j = blockIdx.x * 256 + threadIdx.x;
    if (j < KC * DD) out_c[j] = c[j];
    if (j < KC) {
        const float* row = c + j * DD;
        float r[8];
#pragma unroll
        for (int t = 0; t < 8; ++t) r[t] = __fmul_rn(row[t], row[t]);
#pragma unroll
        for (int b = 1; b < 8; ++b) {
#pragma unroll
            for (int t = 0; t < 8; ++t)
                r[t] = __fadd_rn(r[t], __fmul_rn(row[8 * b + t], row[8 * b + t]));
        }
        c_sq[j] = __fadd_rn(__fadd_rn(__fadd_rn(r[0], r[1]), __fadd_rn(r[2], r[3])),
                            __fadd_rn(__fadd_rn(r[4], r[5]), __fadd_rn(r[6], r[7])));
    }
}

// x_sq with numpy's pairwise-8 summation order (square rounded separately).
__device__ __forceinline__ float xsq_pairwise8(const float* xv) {
    float r[8];
#pragma unroll
    for (int t = 0; t < 8; ++t) r[t] = __fmul_rn(xv[t], xv[t]);
#pragma unroll
    for (int b = 1; b < 8; ++b) {
#pragma unroll
        for (int t = 0; t < 8; ++t)
            r[t] = __fadd_rn(r[t], __fmul_rn(xv[8 * b + t], xv[8 * b + t]));
    }
    return __fadd_rn(__fadd_rn(__fadd_rn(r[0], r[1]), __fadd_rn(r[2], r[3])),
                     __fadd_rn(__fadd_rn(r[4], r[5]), __fadd_rn(r[6], r[7])));
}

// Kernel 2: two points per thread. x rows pinned in VGPRs (asm pin prevents the
// compiler from rematerializing the loads inside the k-loop, which is what
// VGPR_Count=40 showed it was doing). Centroid rows read wave-uniformly ->
// s_load into SGPRs; each scalar value feeds two fma chains (points a,b).
__global__ __launch_bounds__(256, 1) void assign2_kernel(const float* __restrict__ x,
                                                         const float* __restrict__ c,
                                                         const float* __restrict__ c_sq,
                                                         float* __restrict__ out_assign) {
    int gid = blockIdx.x * 256 + threadIdx.x;  // 0 .. HALF-1

    float xa[DD], xb[DD];
    const float4* pa = reinterpret_cast<const float4*>(x + (size_t)gid * DD);
    const float4* pb = reinterpret_cast<const float4*>(x + (size_t)(gid + HALF) * DD);
#pragma unroll
    for (int q = 0; q < DD / 4; ++q) {
        float4 va = pa[q];
        float4 vb = pb[q];
        xa[4 * q + 0] = va.x; xa[4 * q + 1] = va.y;
        xa[4 * q + 2] = va.z; xa[4 * q + 3] = va.w;
        xb[4 * q + 0] = vb.x; xb[4 * q + 1] = vb.y;
        xb[4 * q + 2] = vb.z; xb[4 * q + 3] = vb.w;
    }
    // Pin every x element into a VGPR: the value now originates from an asm
    // result, so the load cannot be rematerialized inside the k-loop.
#pragma unroll
    for (int d = 0; d < DD; ++d) {
        asm("" : "+v"(xa[d]));
        asm("" : "+v"(xb[d]));
    }

    float xsa = xsq_pairwise8(xa);
    float xsb = xsq_pairwise8(xb);

    float best_a = INFINITY, best_b = INFINITY;
    int bka = 0, bkb = 0;

    for (int k = 0; k < KC; ++k) {
        const float* crow = c + (size_t)k * DD;
        float a0 = 0.f, a1 = 0.f, a2 = 0.f, a3 = 0.f;
        float b0 = 0.f, b1 = 0.f, b2 = 0.f, b3 = 0.f;
#pragma unroll
        for (int d = 0; d < DD; d += 4) {
            float c0 = crow[d + 0], c1 = crow[d + 1], c2 = crow[d + 2], c3 = crow[d + 3];
            a0 = __fmaf_rn(xa[d + 0], c0, a0);
            a1 = __fmaf_rn(xa[d + 1], c1, a1);
            a2 = __fmaf_rn(xa[d + 2], c2, a2);
            a3 = __fmaf_rn(xa[d + 3], c3, a3);
            b0 = __fmaf_rn(xb[d + 0], c0, b0);
            b1 = __fmaf_rn(xb[d + 1], c1, b1);
            b2 = __fmaf_rn(xb[d + 2], c2, b2);
            b3 = __fmaf_rn(xb[d + 3], c3, b3);
        }
        float acc_a = __fadd_rn(__fadd_rn(a0, a1), __fadd_rn(a2, a3));
        float acc_b = __fadd_rn(__fadd_rn(b0, b1), __fadd_rn(b2, b3));
        float cs = c_sq[k];
        // Reference rounding: fl(fl(x_sq + c_sq) - 2*cross); -2*acc is exact,
        // so fmaf(-2, acc, t) is bit-identical to fadd(t, -2*acc).
        float ta = __fadd_rn(xsa, cs);
        float tb = __fadd_rn(xsb, cs);
        float da = __fmaf_rn(-2.0f, acc_a, ta);
        float db = __fmaf_rn(-2.0f, acc_b, tb);
        if (da < best_a) { best_a = da; bka = k; }  // strict <: first index wins
        if (db < best_b) { best_b = db; bkb = k; }
    }
    out_assign[gid] = (float)bka;
    out_assign[gid + HALF] = (float)bkb;
}

extern "C" void kernel_launch(void* const* d_in, const int* in_sizes, int n_in,
                              void* d_out, int out_size, void* d_ws, size_t ws_size,
                              hipStream_t stream) {
    const float* x = (const float*)d_in[0];
    const float* c = (const float*)d_in[1];
    float* out = (float*)d_out;
    float* c_sq = (float*)d_ws;

    prep_kernel<<<(KC * DD + 255) / 256, 256, 0, stream>>>(c, out, c_sq);
    assign2_kernel<<<HALF / 256, 256, 0, stream>>>(x, c, c_sq, out + KC * DD);
}